// Round 1
// baseline (2557.686 us; speedup 1.0000x reference)
//
#include <hip/hip_runtime.h>
#include <cstdint>
#include <cstddef>

// ---------------------------------------------------------------------------
// JambaMambaBlock on MI355X (gfx950)
// Pipeline: rmsnorm -> GEMM1(in_proj) -> depthwise conv+silu -> GEMM2(x_proj)
//           -> sequential SSM scan (+gate) -> GEMM3(out_proj, +residual)
// GEMMs: bf16 MFMA 16x16x32, 128x128 tile, global_load_lds(16B) staging.
// ---------------------------------------------------------------------------

typedef __bf16 bf16_t;
typedef __attribute__((ext_vector_type(8))) __bf16 bf16x8;
typedef __attribute__((ext_vector_type(4))) __bf16 bf16x4;
typedef __attribute__((ext_vector_type(4))) float f32x4;

#define D_MODEL 2048
#define D_STATE 16
#define B_SZ 2
#define T_LEN 2048
#define N_ROWS (B_SZ * T_LEN)        // 4096
#define N_PAD  2176                  // x_proj rows padded 2080 -> 17*128

__device__ __forceinline__ void load_lds16(const void* g, void* l) {
    __builtin_amdgcn_global_load_lds(
        (const __attribute__((address_space(1))) void*)(uintptr_t)g,
        (__attribute__((address_space(3))) void*)(uintptr_t)l,
        16, 0, 0);
}

// ---------------- weight casts ----------------
__global__ __launch_bounds__(256) void cast_bf16_vec(
    const float* __restrict__ s, bf16_t* __restrict__ d, int n4)
{
    int i = blockIdx.x * 256 + threadIdx.x;
    if (i < n4) {
        f32x4 v = ((const f32x4*)s)[i];
        ((bf16x4*)d)[i] = __builtin_convertvector(v, bf16x4);
    }
}

// x_proj_w (2080 x 2048) -> bf16 padded to (2176 x 2048), pad rows zero
__global__ __launch_bounds__(256) void cast_pad_w2(
    const float* __restrict__ s, bf16_t* __restrict__ d)
{
    int i = blockIdx.x * 256 + threadIdx.x;   // over 2176*2048
    int row = i >> 11;
    int col = i & 2047;
    float v = (row < 2080) ? s[(size_t)row * 2048 + col] : 0.f;
    d[i] = (bf16_t)v;
}

// ---------------- rmsnorm -> bf16 ----------------
__global__ __launch_bounds__(256) void rmsnorm_kernel(
    const float* __restrict__ x, const float* __restrict__ w,
    bf16_t* __restrict__ xn)
{
    int row = blockIdx.x;
    int tid = threadIdx.x;
    const float* xr = x + (size_t)row * D_MODEL;
    float ss = 0.f;
    for (int i = tid; i < D_MODEL; i += 256) { float v = xr[i]; ss = fmaf(v, v, ss); }
    #pragma unroll
    for (int o = 32; o > 0; o >>= 1) ss += __shfl_down(ss, o, 64);
    __shared__ float red[4];
    if ((tid & 63) == 0) red[tid >> 6] = ss;
    __syncthreads();
    float tot = red[0] + red[1] + red[2] + red[3];
    float scale = rsqrtf(tot * (1.f / D_MODEL) + 1e-6f);
    bf16_t* xo = xn + (size_t)row * D_MODEL;
    for (int i = tid; i < D_MODEL; i += 256) xo[i] = (bf16_t)(xr[i] * scale * w[i]);
}

// ---------------- bf16 GEMM: C[M,N] = A[M,K] @ B[N,K]^T (+addend) ----------
// grid: (M/128, N/128), 256 threads (4 waves, 2x2 of 64x64 regions)
__global__ __launch_bounds__(256) void gemm_bt(
    const bf16_t* __restrict__ A, const bf16_t* __restrict__ B,
    float* __restrict__ C, const float* __restrict__ add,
    int K, int ldc)
{
    __shared__ __align__(16) bf16_t lA[128 * 32];
    __shared__ __align__(16) bf16_t lB[128 * 32];
    const int tid = threadIdx.x;
    const int bm = blockIdx.x, bn = blockIdx.y;

    // staging: thread t loads 8 contiguous bf16 (16B); 2 chunks each for A,B
    const int rA = tid >> 2;            // 0..63
    const int cA = (tid & 3) * 8;       // 0,8,16,24
    const bf16_t* aSrc = A + ((size_t)bm * 128 + rA) * K + cA;
    const bf16_t* bSrc = B + ((size_t)bn * 128 + rA) * K + cA;

    const int lane = tid & 63;
    const int wave = tid >> 6;
    const int wm = (wave & 1) * 64;
    const int wn = (wave >> 1) * 64;
    const int fr = lane & 15;
    const int quad = lane >> 4;
    const int aOff = (wm + fr) * 32 + quad * 8;
    const int bOff = (wn + fr) * 32 + quad * 8;

    f32x4 acc[4][4];
    #pragma unroll
    for (int i = 0; i < 4; ++i)
        #pragma unroll
        for (int j = 0; j < 4; ++j) acc[i][j] = {0.f, 0.f, 0.f, 0.f};

    const int kIters = K >> 5;
    for (int kt = 0; kt < kIters; ++kt) {
        load_lds16(aSrc,                 &lA[tid * 8]);
        load_lds16(aSrc + (size_t)64 * K, &lA[2048 + tid * 8]);
        load_lds16(bSrc,                 &lB[tid * 8]);
        load_lds16(bSrc + (size_t)64 * K, &lB[2048 + tid * 8]);
        aSrc += 32; bSrc += 32;
        __syncthreads();   // drains vmcnt (global_load_lds) + lgkm

        bf16x8 af[4], bv[4];
        #pragma unroll
        for (int i = 0; i < 4; ++i) af[i] = *(const bf16x8*)(&lA[aOff + i * 512]);
        #pragma unroll
        for (int j = 0; j < 4; ++j) bv[j] = *(const bf16x8*)(&lB[bOff + j * 512]);
        #pragma unroll
        for (int i = 0; i < 4; ++i)
            #pragma unroll
            for (int j = 0; j < 4; ++j)
                acc[i][j] = __builtin_amdgcn_mfma_f32_16x16x32_bf16(
                    af[i], bv[j], acc[i][j], 0, 0, 0);
        __syncthreads();
    }

    // epilogue: D row = quad*4 + reg, col = lane&15  (verified m89/m91 layout)
    const size_t row0 = (size_t)bm * 128 + wm + quad * 4;
    const size_t col0 = (size_t)bn * 128 + wn + fr;
    #pragma unroll
    for (int i = 0; i < 4; ++i) {
        #pragma unroll
        for (int r = 0; r < 4; ++r) {
            size_t row = row0 + i * 16 + r;
            float* crow = C + row * (size_t)ldc + col0;
            const float* arow = add ? (add + row * (size_t)ldc + col0) : (const float*)nullptr;
            #pragma unroll
            for (int j = 0; j < 4; ++j) {
                float v = acc[i][j][r];
                if (arow) v += arow[j * 16];
                crow[j * 16] = v;
            }
        }
    }
}

// ---------------- depthwise causal conv(4) + silu ----------------
// xz rows (B*T) pitch 4096; x-branch = cols [0,2048)
__global__ __launch_bounds__(256) void conv_silu_kernel(
    const float* __restrict__ xz, const float* __restrict__ cw,
    const float* __restrict__ cb, float* __restrict__ xs_f,
    bf16_t* __restrict__ xs_b)
{
    int id = blockIdx.x * 256 + threadIdx.x;  // B*(T/8)*D = 2^20
    int d  = id & 2047;
    int tb = (id >> 11) & 255;
    int b  = id >> 19;
    float w0 = cw[d * 4 + 0], w1 = cw[d * 4 + 1], w2 = cw[d * 4 + 2], w3 = cw[d * 4 + 3];
    float bias = cb[d];
    int t0 = t0 = tb * 8;
    size_t base = (size_t)b * T_LEN;
    float v[11];
    #pragma unroll
    for (int i = 0; i < 11; ++i) {
        int t = t0 - 3 + i;
        v[i] = (t >= 0) ? xz[(base + t) * 4096 + d] : 0.f;
    }
    #pragma unroll
    for (int j = 0; j < 8; ++j) {
        float s = bias + w0 * v[j] + w1 * v[j + 1] + w2 * v[j + 2] + w3 * v[j + 3];
        float sl = s / (1.f + __expf(-s));
        size_t o = (base + t0 + j) * D_MODEL + d;
        xs_f[o] = sl;
        xs_b[o] = (bf16_t)sl;
    }
}

// ---------------- sequential SSM scan + gate ----------------
// 1 thread per (b,d); 64 blocks x 64 threads
__global__ __launch_bounds__(64) void scan_kernel(
    const float* __restrict__ proj, const float* __restrict__ xs,
    const float* __restrict__ xz, const float* __restrict__ A_log,
    const float* __restrict__ Dv, const float* __restrict__ h_in,
    bf16_t* __restrict__ yg, float* __restrict__ h_out)
{
    int g  = blockIdx.x * 64 + threadIdx.x;  // 0..4095
    int b  = g >> 11;
    int dd = g & 2047;
    float A2[D_STATE], h[D_STATE];
    #pragma unroll
    for (int n = 0; n < D_STATE; ++n) {
        A2[n] = -__expf(A_log[dd * D_STATE + n]) * 1.4426950408889634f; // *log2(e)
        h[n]  = h_in[((size_t)b * D_MODEL + dd) * D_STATE + n];
    }
    float Dd = Dv[dd];
    for (int t = 0; t < T_LEN; ++t) {
        size_t row = (size_t)b * T_LEN + t;
        const float* pr = proj + row * N_PAD;
        float draw = pr[dd];
        float xv = xs[row * D_MODEL + dd];
        float zv = xz[row * 4096 + D_MODEL + dd];
        // softplus (stable)
        float da = fmaxf(draw, 0.f) + __logf(1.f + __expf(-fabsf(draw)));
        float dx = da * xv;
        float y = Dd * xv;
        const f32x4* bc = (const f32x4*)(pr + D_MODEL);
        f32x4 Bq[4], Cq[4];
        #pragma unroll
        for (int q = 0; q < 4; ++q) { Bq[q] = bc[q]; Cq[q] = bc[4 + q]; }
        #pragma unroll
        for (int n = 0; n < D_STATE; ++n) {
            float Bt = Bq[n >> 2][n & 3];
            float Ct = Cq[n >> 2][n & 3];
            float ab = exp2f(da * A2[n]);
            h[n] = fmaf(ab, h[n], dx * Bt);
            y = fmaf(h[n], Ct, y);
        }
        float sz = zv / (1.f + __expf(-zv));
        yg[row * D_MODEL + dd] = (bf16_t)(y * sz);
    }
    #pragma unroll
    for (int n = 0; n < D_STATE; ++n)
        h_out[((size_t)b * D_MODEL + dd) * D_STATE + n] = h[n];
}

// ---------------------------------------------------------------------------
extern "C" void kernel_launch(void* const* d_in, const int* in_sizes, int n_in,
                              void* d_out, int out_size, void* d_ws, size_t ws_size,
                              hipStream_t stream)
{
    const float* x    = (const float*)d_in[0];
    const float* h0   = (const float*)d_in[1];
    const float* nw   = (const float*)d_in[2];
    const float* w_in = (const float*)d_in[3];
    const float* cw   = (const float*)d_in[4];
    const float* cb   = (const float*)d_in[5];
    const float* w_x  = (const float*)d_in[6];
    const float* alog = (const float*)d_in[7];
    const float* dv   = (const float*)d_in[8];
    const float* w_out= (const float*)d_in[9];
    float* out  = (float*)d_out;
    float* hout = out + (size_t)N_ROWS * D_MODEL;

    char* ws = (char*)d_ws;
    size_t off = 0;
    auto alloc = [&](size_t bytes) -> void* {
        void* p = ws + off;
        off += (bytes + 255) & ~(size_t)255;
        return p;
    };
    bf16_t* W1  = (bf16_t*)alloc((size_t)4096 * 2048 * 2);   // in_proj bf16
    bf16_t* W2  = (bf16_t*)alloc((size_t)N_PAD * 2048 * 2);  // x_proj bf16 padded
    bf16_t* W3  = (bf16_t*)alloc((size_t)2048 * 2048 * 2);   // out_proj bf16
    bf16_t* XN  = (bf16_t*)alloc((size_t)N_ROWS * 2048 * 2); // normed x bf16
    float*  XZ  = (float*) alloc((size_t)N_ROWS * 4096 * 4); // in_proj out
    float*  XSf = (float*) alloc((size_t)N_ROWS * 2048 * 4); // conv+silu fp32
    float*  PROJ= (float*) alloc((size_t)N_ROWS * N_PAD * 4);// x_proj out
    // aliases (lifetimes disjoint in stream order):
    bf16_t* XSb = W1;   // conv output bf16 (W1 dead after GEMM1)
    bf16_t* YG  = XN;   // gated y bf16    (XN dead after GEMM1)

    // weight casts
    cast_bf16_vec<<<(4096 * 2048 / 4) / 256, 256, 0, stream>>>(w_in, W1, 4096 * 2048 / 4);
    cast_pad_w2 <<<(N_PAD * 2048) / 256, 256, 0, stream>>>(w_x, W2);
    cast_bf16_vec<<<(2048 * 2048 / 4) / 256, 256, 0, stream>>>(w_out, W3, 2048 * 2048 / 4);

    // 1) rmsnorm
    rmsnorm_kernel<<<N_ROWS, 256, 0, stream>>>(x, nw, XN);
    // 2) xz = xn @ W_in^T   (M=4096, N=4096, K=2048)
    gemm_bt<<<dim3(32, 32), 256, 0, stream>>>(XN, W1, XZ, nullptr, 2048, 4096);
    // 3) conv + silu
    conv_silu_kernel<<<(B_SZ * (T_LEN / 8) * D_MODEL) / 256, 256, 0, stream>>>(XZ, cw, cb, XSf, XSb);
    // 4) proj = xssm @ W_x^T  (N=2176 padded)
    gemm_bt<<<dim3(32, N_PAD / 128), 256, 0, stream>>>(XSb, W2, PROJ, nullptr, 2048, N_PAD);
    // 5) scan + gate
    scan_kernel<<<64, 64, 0, stream>>>(PROJ, XSf, XZ, alog, dv, h0, YG, hout);
    // 6) out = x + yg @ W_out^T
    gemm_bt<<<dim3(32, 16), 256, 0, stream>>>(YG, W3, out, x, 2048, 2048);

    (void)in_sizes; (void)n_in; (void)out_size; (void)ws_size;
}

// Round 2
// 625.885 us; speedup vs baseline: 4.0865x; 4.0865x over previous
//
#include <hip/hip_runtime.h>
#include <cstdint>
#include <cstddef>

// ---------------------------------------------------------------------------
// JambaMambaBlock on MI355X (gfx950)
// Pipeline: rmsnorm -> GEMM1(in_proj) -> depthwise conv+silu -> GEMM2(x_proj)
//           -> chunked SSM scan (3 phases) -> GEMM3(out_proj, +residual)
// GEMMs: bf16 MFMA 16x16x32, 128x128 tile, global_load_lds(16B) staging.
// Scan: T=2048 split into 32 chunks of 64; phase1 local scan (zero-init),
//       phase2 serial chunk combine (also yields h_out), phase3 replay with
//       correct chunk-initial states + gate.  64x more parallelism, 2x work.
// ---------------------------------------------------------------------------

typedef __bf16 bf16_t;
typedef __attribute__((ext_vector_type(8))) __bf16 bf16x8;
typedef __attribute__((ext_vector_type(4))) __bf16 bf16x4;
typedef __attribute__((ext_vector_type(4))) float f32x4;

#define D_MODEL 2048
#define D_STATE 16
#define B_SZ 2
#define T_LEN 2048
#define N_ROWS (B_SZ * T_LEN)        // 4096
#define N_PAD  2176                  // x_proj rows padded 2080 -> 17*128
#define N_CHUNK 32
#define L_CHUNK (T_LEN / N_CHUNK)    // 64
#define LOG2E 1.4426950408889634f

__device__ __forceinline__ void load_lds16(const void* g, void* l) {
    __builtin_amdgcn_global_load_lds(
        (const __attribute__((address_space(1))) void*)(uintptr_t)g,
        (__attribute__((address_space(3))) void*)(uintptr_t)l,
        16, 0, 0);
}

// ---------------- weight casts ----------------
__global__ __launch_bounds__(256) void cast_bf16_vec(
    const float* __restrict__ s, bf16_t* __restrict__ d, int n4)
{
    int i = blockIdx.x * 256 + threadIdx.x;
    if (i < n4) {
        f32x4 v = ((const f32x4*)s)[i];
        ((bf16x4*)d)[i] = __builtin_convertvector(v, bf16x4);
    }
}

// x_proj_w (2080 x 2048) -> bf16 padded to (2176 x 2048), pad rows zero
__global__ __launch_bounds__(256) void cast_pad_w2(
    const float* __restrict__ s, bf16_t* __restrict__ d)
{
    int i = blockIdx.x * 256 + threadIdx.x;   // over 2176*2048
    int row = i >> 11;
    int col = i & 2047;
    float v = (row < 2080) ? s[(size_t)row * 2048 + col] : 0.f;
    d[i] = (bf16_t)v;
}

// ---------------- rmsnorm -> bf16 ----------------
__global__ __launch_bounds__(256) void rmsnorm_kernel(
    const float* __restrict__ x, const float* __restrict__ w,
    bf16_t* __restrict__ xn)
{
    int row = blockIdx.x;
    int tid = threadIdx.x;
    const float* xr = x + (size_t)row * D_MODEL;
    float ss = 0.f;
    for (int i = tid; i < D_MODEL; i += 256) { float v = xr[i]; ss = fmaf(v, v, ss); }
    #pragma unroll
    for (int o = 32; o > 0; o >>= 1) ss += __shfl_down(ss, o, 64);
    __shared__ float red[4];
    if ((tid & 63) == 0) red[tid >> 6] = ss;
    __syncthreads();
    float tot = red[0] + red[1] + red[2] + red[3];
    float scale = rsqrtf(tot * (1.f / D_MODEL) + 1e-6f);
    bf16_t* xo = xn + (size_t)row * D_MODEL;
    for (int i = tid; i < D_MODEL; i += 256) xo[i] = (bf16_t)(xr[i] * scale * w[i]);
}

// ---------------- bf16 GEMM: C[M,N] = A[M,K] @ B[N,K]^T (+addend) ----------
// grid: (M/128, N/128), 256 threads (4 waves, 2x2 of 64x64 regions)
__global__ __launch_bounds__(256) void gemm_bt(
    const bf16_t* __restrict__ A, const bf16_t* __restrict__ B,
    float* __restrict__ C, const float* __restrict__ add,
    int K, int ldc)
{
    __shared__ __align__(16) bf16_t lA[128 * 32];
    __shared__ __align__(16) bf16_t lB[128 * 32];
    const int tid = threadIdx.x;
    const int bm = blockIdx.x, bn = blockIdx.y;

    const int rA = tid >> 2;            // 0..63
    const int cA = (tid & 3) * 8;       // 0,8,16,24
    const bf16_t* aSrc = A + ((size_t)bm * 128 + rA) * K + cA;
    const bf16_t* bSrc = B + ((size_t)bn * 128 + rA) * K + cA;

    const int lane = tid & 63;
    const int wave = tid >> 6;
    const int wm = (wave & 1) * 64;
    const int wn = (wave >> 1) * 64;
    const int fr = lane & 15;
    const int quad = lane >> 4;
    const int aOff = (wm + fr) * 32 + quad * 8;
    const int bOff = (wn + fr) * 32 + quad * 8;

    f32x4 acc[4][4];
    #pragma unroll
    for (int i = 0; i < 4; ++i)
        #pragma unroll
        for (int j = 0; j < 4; ++j) acc[i][j] = {0.f, 0.f, 0.f, 0.f};

    const int kIters = K >> 5;
    for (int kt = 0; kt < kIters; ++kt) {
        load_lds16(aSrc,                  &lA[tid * 8]);
        load_lds16(aSrc + (size_t)64 * K, &lA[2048 + tid * 8]);
        load_lds16(bSrc,                  &lB[tid * 8]);
        load_lds16(bSrc + (size_t)64 * K, &lB[2048 + tid * 8]);
        aSrc += 32; bSrc += 32;
        __syncthreads();

        bf16x8 af[4], bv[4];
        #pragma unroll
        for (int i = 0; i < 4; ++i) af[i] = *(const bf16x8*)(&lA[aOff + i * 512]);
        #pragma unroll
        for (int j = 0; j < 4; ++j) bv[j] = *(const bf16x8*)(&lB[bOff + j * 512]);
        #pragma unroll
        for (int i = 0; i < 4; ++i)
            #pragma unroll
            for (int j = 0; j < 4; ++j)
                acc[i][j] = __builtin_amdgcn_mfma_f32_16x16x32_bf16(
                    af[i], bv[j], acc[i][j], 0, 0, 0);
        __syncthreads();
    }

    const size_t row0 = (size_t)bm * 128 + wm + quad * 4;
    const size_t col0 = (size_t)bn * 128 + wn + fr;
    #pragma unroll
    for (int i = 0; i < 4; ++i) {
        #pragma unroll
        for (int r = 0; r < 4; ++r) {
            size_t row = row0 + i * 16 + r;
            float* crow = C + row * (size_t)ldc + col0;
            const float* arow = add ? (add + row * (size_t)ldc + col0) : (const float*)nullptr;
            #pragma unroll
            for (int j = 0; j < 4; ++j) {
                float v = acc[i][j][r];
                if (arow) v += arow[j * 16];
                crow[j * 16] = v;
            }
        }
    }
}

// ---------------- depthwise causal conv(4) + silu ----------------
__global__ __launch_bounds__(256) void conv_silu_kernel(
    const float* __restrict__ xz, const float* __restrict__ cw,
    const float* __restrict__ cb, float* __restrict__ xs_f,
    bf16_t* __restrict__ xs_b)
{
    int id = blockIdx.x * 256 + threadIdx.x;  // B*(T/8)*D = 2^20
    int d  = id & 2047;
    int tb = (id >> 11) & 255;
    int b  = id >> 19;
    float w0 = cw[d * 4 + 0], w1 = cw[d * 4 + 1], w2 = cw[d * 4 + 2], w3 = cw[d * 4 + 3];
    float bias = cb[d];
    int t0 = tb * 8;
    size_t base = (size_t)b * T_LEN;
    float v[11];
    #pragma unroll
    for (int i = 0; i < 11; ++i) {
        int t = t0 - 3 + i;
        v[i] = (t >= 0) ? xz[(base + t) * 4096 + d] : 0.f;
    }
    #pragma unroll
    for (int j = 0; j < 8; ++j) {
        float s = bias + w0 * v[j] + w1 * v[j + 1] + w2 * v[j + 2] + w3 * v[j + 3];
        float sl = s / (1.f + __expf(-s));
        size_t o = (base + t0 + j) * D_MODEL + d;
        xs_f[o] = sl;
        xs_b[o] = (bf16_t)sl;
    }
}

// ---------------- chunked SSM scan ----------------
// group gi in [0,2048): c = gi&31, dg = (gi>>5)&31, b = gi>>10; lane -> dd
// scratch layout: [c][b][dd][n] flat = (c*4096 + b*2048 + dd)*16 + n

// phase 1: local scan with zero init; store decay product + local final state
__global__ __launch_bounds__(256) void scan_phase1(
    const float* __restrict__ proj, const float* __restrict__ xs,
    const float* __restrict__ A_log,
    float* __restrict__ Aprod, float* __restrict__ hfin)
{
    int gi   = blockIdx.x * 4 + (threadIdx.x >> 6);
    int lane = threadIdx.x & 63;
    int c  = gi & 31;
    int dg = (gi >> 5) & 31;
    int b  = gi >> 10;
    int dd = dg * 64 + lane;

    float A2[D_STATE], h[D_STATE], Ap[D_STATE];
    #pragma unroll
    for (int n = 0; n < D_STATE; ++n) {
        A2[n] = -__expf(A_log[dd * D_STATE + n]) * LOG2E;
        h[n] = 0.f; Ap[n] = 1.f;
    }
    int t0 = c * L_CHUNK;
    for (int t = t0; t < t0 + L_CHUNK; ++t) {
        size_t row = (size_t)b * T_LEN + t;
        const float* pr = proj + row * N_PAD;
        float draw = pr[dd];
        float xv = xs[row * D_MODEL + dd];
        float da = fmaxf(draw, 0.f) + __logf(1.f + __expf(-fabsf(draw)));
        float dx = da * xv;
        const f32x4* bc = (const f32x4*)(pr + D_MODEL);
        f32x4 Bq[4];
        #pragma unroll
        for (int q = 0; q < 4; ++q) Bq[q] = bc[q];
        #pragma unroll
        for (int n = 0; n < D_STATE; ++n) {
            float a = exp2f(da * A2[n]);
            Ap[n] *= a;
            h[n] = fmaf(a, h[n], dx * Bq[n >> 2][n & 3]);
        }
    }
    size_t o = ((size_t)c * 4096 + b * 2048 + dd) * D_STATE;
    #pragma unroll
    for (int q = 0; q < 4; ++q) {
        ((f32x4*)(Aprod + o))[q] = f32x4{Ap[4*q], Ap[4*q+1], Ap[4*q+2], Ap[4*q+3]};
        ((f32x4*)(hfin  + o))[q] = f32x4{h[4*q],  h[4*q+1],  h[4*q+2],  h[4*q+3]};
    }
}

// phase 2: serial combine across chunks. In-place converts hfin -> h_init
// per chunk, and writes the exact final state h_out.
__global__ __launch_bounds__(256) void scan_phase2(
    const float* __restrict__ h_in, const float* __restrict__ Aprod,
    float* __restrict__ hfin, float* __restrict__ h_out)
{
    int g = blockIdx.x * 256 + threadIdx.x;   // (b*2048+dd)*16+n, 65536 total
    float h = h_in[g];
    for (int c = 0; c < N_CHUNK; ++c) {
        size_t o = (size_t)c * 65536 + g;
        float a   = Aprod[o];
        float loc = hfin[o];
        hfin[o] = h;                 // becomes h_init for chunk c
        h = fmaf(a, h, loc);
    }
    h_out[g] = h;
}

// phase 3: replay each chunk from its exact initial state; emit gated y.
__global__ __launch_bounds__(256) void scan_phase3(
    const float* __restrict__ proj, const float* __restrict__ xs,
    const float* __restrict__ xz, const float* __restrict__ A_log,
    const float* __restrict__ Dv, const float* __restrict__ hinit,
    bf16_t* __restrict__ yg)
{
    int gi   = blockIdx.x * 4 + (threadIdx.x >> 6);
    int lane = threadIdx.x & 63;
    int c  = gi & 31;
    int dg = (gi >> 5) & 31;
    int b  = gi >> 10;
    int dd = dg * 64 + lane;

    float A2[D_STATE], h[D_STATE];
    size_t o = ((size_t)c * 4096 + b * 2048 + dd) * D_STATE;
    #pragma unroll
    for (int n = 0; n < D_STATE; ++n) {
        A2[n] = -__expf(A_log[dd * D_STATE + n]) * LOG2E;
        h[n]  = hinit[o + n];
    }
    float Dd = Dv[dd];
    int t0 = c * L_CHUNK;
    for (int t = t0; t < t0 + L_CHUNK; ++t) {
        size_t row = (size_t)b * T_LEN + t;
        const float* pr = proj + row * N_PAD;
        float draw = pr[dd];
        float xv = xs[row * D_MODEL + dd];
        float zv = xz[row * 4096 + D_MODEL + dd];
        float da = fmaxf(draw, 0.f) + __logf(1.f + __expf(-fabsf(draw)));
        float dx = da * xv;
        float y = Dd * xv;
        const f32x4* bc = (const f32x4*)(pr + D_MODEL);
        f32x4 Bq[4], Cq[4];
        #pragma unroll
        for (int q = 0; q < 4; ++q) { Bq[q] = bc[q]; Cq[q] = bc[4 + q]; }
        #pragma unroll
        for (int n = 0; n < D_STATE; ++n) {
            float a = exp2f(da * A2[n]);
            h[n] = fmaf(a, h[n], dx * Bq[n >> 2][n & 3]);
            y = fmaf(h[n], Cq[n >> 2][n & 3], y);
        }
        float sz = zv / (1.f + __expf(-zv));
        yg[row * D_MODEL + dd] = (bf16_t)(y * sz);
    }
}

// ---------------------------------------------------------------------------
extern "C" void kernel_launch(void* const* d_in, const int* in_sizes, int n_in,
                              void* d_out, int out_size, void* d_ws, size_t ws_size,
                              hipStream_t stream)
{
    const float* x    = (const float*)d_in[0];
    const float* h0   = (const float*)d_in[1];
    const float* nw   = (const float*)d_in[2];
    const float* w_in = (const float*)d_in[3];
    const float* cw   = (const float*)d_in[4];
    const float* cb   = (const float*)d_in[5];
    const float* w_x  = (const float*)d_in[6];
    const float* alog = (const float*)d_in[7];
    const float* dv   = (const float*)d_in[8];
    const float* w_out= (const float*)d_in[9];
    float* out  = (float*)d_out;
    float* hout = out + (size_t)N_ROWS * D_MODEL;

    char* ws = (char*)d_ws;
    size_t off = 0;
    auto alloc = [&](size_t bytes) -> void* {
        void* p = ws + off;
        off += (bytes + 255) & ~(size_t)255;
        return p;
    };
    bf16_t* W1  = (bf16_t*)alloc((size_t)4096 * 2048 * 2);   // in_proj bf16
    bf16_t* W2  = (bf16_t*)alloc((size_t)N_PAD * 2048 * 2);  // x_proj bf16 padded
    bf16_t* W3  = (bf16_t*)alloc((size_t)2048 * 2048 * 2);   // out_proj bf16
    bf16_t* XN  = (bf16_t*)alloc((size_t)N_ROWS * 2048 * 2); // normed x bf16
    float*  XZ  = (float*) alloc((size_t)N_ROWS * 4096 * 4); // in_proj out
    float*  XSf = (float*) alloc((size_t)N_ROWS * 2048 * 4); // conv+silu fp32
    float*  PROJ= (float*) alloc((size_t)N_ROWS * N_PAD * 4);// x_proj out
    // aliases (lifetimes disjoint in stream order):
    bf16_t* XSb = W1;                  // conv bf16 out (W1 dead after GEMM1)
    bf16_t* YG  = XN;                  // gated y bf16  (XN dead after GEMM1)
    // scan scratch: W1 region is dead again after GEMM2 (XSb consumed).
    // Aprod (8.39 MB) + hfin (8.39 MB) == exactly the 16.78 MB W1 region.
    float* APROD = (float*)W1;
    float* HFIN  = APROD + (size_t)N_CHUNK * 4096 * D_STATE;

    // weight casts
    cast_bf16_vec<<<(4096 * 2048 / 4) / 256, 256, 0, stream>>>(w_in, W1, 4096 * 2048 / 4);
    cast_pad_w2 <<<(N_PAD * 2048) / 256, 256, 0, stream>>>(w_x, W2);
    cast_bf16_vec<<<(2048 * 2048 / 4) / 256, 256, 0, stream>>>(w_out, W3, 2048 * 2048 / 4);

    // 1) rmsnorm
    rmsnorm_kernel<<<N_ROWS, 256, 0, stream>>>(x, nw, XN);
    // 2) xz = xn @ W_in^T   (M=4096, N=4096, K=2048)
    gemm_bt<<<dim3(32, 32), 256, 0, stream>>>(XN, W1, XZ, nullptr, 2048, 4096);
    // 3) conv + silu
    conv_silu_kernel<<<(B_SZ * (T_LEN / 8) * D_MODEL) / 256, 256, 0, stream>>>(XZ, cw, cb, XSf, XSb);
    // 4) proj = xssm @ W_x^T  (N=2176 padded)
    gemm_bt<<<dim3(32, N_PAD / 128), 256, 0, stream>>>(XSb, W2, PROJ, nullptr, 2048, N_PAD);
    // 5) chunked scan
    scan_phase1<<<512, 256, 0, stream>>>(PROJ, XSf, alog, APROD, HFIN);
    scan_phase2<<<256, 256, 0, stream>>>(h0, APROD, HFIN, hout);
    scan_phase3<<<512, 256, 0, stream>>>(PROJ, XSf, XZ, alog, dv, HFIN, YG);
    // 6) out = x + yg @ W_out^T
    gemm_bt<<<dim3(32, 16), 256, 0, stream>>>(YG, W3, out, x, 2048, 2048);

    (void)in_sizes; (void)n_in; (void)out_size; (void)ws_size;
}

// Round 3
// 606.325 us; speedup vs baseline: 4.2183x; 1.0323x over previous
//
#include <hip/hip_runtime.h>
#include <cstdint>
#include <cstddef>

// ---------------------------------------------------------------------------
// JambaMambaBlock on MI355X (gfx950)
// Pipeline: rmsnorm -> GEMM1(in_proj) -> depthwise conv+silu -> GEMM2(x_proj)
//           -> chunked SSM scan (3 phases) -> GEMM3(out_proj, +residual)
// GEMMs: bf16 MFMA 16x16x32, 128x128 tile, global_load_lds(16B) staging.
// Scan: 32 chunks of 64 steps; D_STATE=16 split across 4 lanes (4 states
//       each) -> 8192 waves (100% of wave slots) for phases 1/3.
// ---------------------------------------------------------------------------

typedef __bf16 bf16_t;
typedef __attribute__((ext_vector_type(8))) __bf16 bf16x8;
typedef __attribute__((ext_vector_type(4))) __bf16 bf16x4;
typedef __attribute__((ext_vector_type(4))) float f32x4;

#define D_MODEL 2048
#define D_STATE 16
#define B_SZ 2
#define T_LEN 2048
#define N_ROWS (B_SZ * T_LEN)        // 4096
#define N_PAD  2176                  // x_proj rows padded 2080 -> 17*128
#define N_CHUNK 32
#define L_CHUNK (T_LEN / N_CHUNK)    // 64
#define LOG2E 1.4426950408889634f

__device__ __forceinline__ void load_lds16(const void* g, void* l) {
    __builtin_amdgcn_global_load_lds(
        (const __attribute__((address_space(1))) void*)(uintptr_t)g,
        (__attribute__((address_space(3))) void*)(uintptr_t)l,
        16, 0, 0);
}

// ---------------- weight casts ----------------
__global__ __launch_bounds__(256) void cast_bf16_vec(
    const float* __restrict__ s, bf16_t* __restrict__ d, int n4)
{
    int i = blockIdx.x * 256 + threadIdx.x;
    if (i < n4) {
        f32x4 v = ((const f32x4*)s)[i];
        ((bf16x4*)d)[i] = __builtin_convertvector(v, bf16x4);
    }
}

// x_proj_w (2080 x 2048) -> bf16 padded to (2176 x 2048), pad rows zero
__global__ __launch_bounds__(256) void cast_pad_w2(
    const float* __restrict__ s, bf16_t* __restrict__ d)
{
    int i = blockIdx.x * 256 + threadIdx.x;   // over 2176*2048
    int row = i >> 11;
    int col = i & 2047;
    float v = (row < 2080) ? s[(size_t)row * 2048 + col] : 0.f;
    d[i] = (bf16_t)v;
}

// ---------------- rmsnorm -> bf16 ----------------
__global__ __launch_bounds__(256) void rmsnorm_kernel(
    const float* __restrict__ x, const float* __restrict__ w,
    bf16_t* __restrict__ xn)
{
    int row = blockIdx.x;
    int tid = threadIdx.x;
    const float* xr = x + (size_t)row * D_MODEL;
    float ss = 0.f;
    for (int i = tid; i < D_MODEL; i += 256) { float v = xr[i]; ss = fmaf(v, v, ss); }
    #pragma unroll
    for (int o = 32; o > 0; o >>= 1) ss += __shfl_down(ss, o, 64);
    __shared__ float red[4];
    if ((tid & 63) == 0) red[tid >> 6] = ss;
    __syncthreads();
    float tot = red[0] + red[1] + red[2] + red[3];
    float scale = rsqrtf(tot * (1.f / D_MODEL) + 1e-6f);
    bf16_t* xo = xn + (size_t)row * D_MODEL;
    for (int i = tid; i < D_MODEL; i += 256) xo[i] = (bf16_t)(xr[i] * scale * w[i]);
}

// ---------------- bf16 GEMM: C[M,N] = A[M,K] @ B[N,K]^T (+addend) ----------
__global__ __launch_bounds__(256) void gemm_bt(
    const bf16_t* __restrict__ A, const bf16_t* __restrict__ B,
    float* __restrict__ C, const float* __restrict__ add,
    int K, int ldc)
{
    __shared__ __align__(16) bf16_t lA[128 * 32];
    __shared__ __align__(16) bf16_t lB[128 * 32];
    const int tid = threadIdx.x;
    const int bm = blockIdx.x, bn = blockIdx.y;

    const int rA = tid >> 2;            // 0..63
    const int cA = (tid & 3) * 8;       // 0,8,16,24
    const bf16_t* aSrc = A + ((size_t)bm * 128 + rA) * K + cA;
    const bf16_t* bSrc = B + ((size_t)bn * 128 + rA) * K + cA;

    const int lane = tid & 63;
    const int wave = tid >> 6;
    const int wm = (wave & 1) * 64;
    const int wn = (wave >> 1) * 64;
    const int fr = lane & 15;
    const int quad = lane >> 4;
    const int aOff = (wm + fr) * 32 + quad * 8;
    const int bOff = (wn + fr) * 32 + quad * 8;

    f32x4 acc[4][4];
    #pragma unroll
    for (int i = 0; i < 4; ++i)
        #pragma unroll
        for (int j = 0; j < 4; ++j) acc[i][j] = {0.f, 0.f, 0.f, 0.f};

    const int kIters = K >> 5;
    for (int kt = 0; kt < kIters; ++kt) {
        load_lds16(aSrc,                  &lA[tid * 8]);
        load_lds16(aSrc + (size_t)64 * K, &lA[2048 + tid * 8]);
        load_lds16(bSrc,                  &lB[tid * 8]);
        load_lds16(bSrc + (size_t)64 * K, &lB[2048 + tid * 8]);
        aSrc += 32; bSrc += 32;
        __syncthreads();

        bf16x8 af[4], bv[4];
        #pragma unroll
        for (int i = 0; i < 4; ++i) af[i] = *(const bf16x8*)(&lA[aOff + i * 512]);
        #pragma unroll
        for (int j = 0; j < 4; ++j) bv[j] = *(const bf16x8*)(&lB[bOff + j * 512]);
        #pragma unroll
        for (int i = 0; i < 4; ++i)
            #pragma unroll
            for (int j = 0; j < 4; ++j)
                acc[i][j] = __builtin_amdgcn_mfma_f32_16x16x32_bf16(
                    af[i], bv[j], acc[i][j], 0, 0, 0);
        __syncthreads();
    }

    const size_t row0 = (size_t)bm * 128 + wm + quad * 4;
    const size_t col0 = (size_t)bn * 128 + wn + fr;
    #pragma unroll
    for (int i = 0; i < 4; ++i) {
        #pragma unroll
        for (int r = 0; r < 4; ++r) {
            size_t row = row0 + i * 16 + r;
            float* crow = C + row * (size_t)ldc + col0;
            const float* arow = add ? (add + row * (size_t)ldc + col0) : (const float*)nullptr;
            #pragma unroll
            for (int j = 0; j < 4; ++j) {
                float v = acc[i][j][r];
                if (arow) v += arow[j * 16];
                crow[j * 16] = v;
            }
        }
    }
}

// ---------------- depthwise causal conv(4) + silu ----------------
__global__ __launch_bounds__(256) void conv_silu_kernel(
    const float* __restrict__ xz, const float* __restrict__ cw,
    const float* __restrict__ cb, float* __restrict__ xs_f,
    bf16_t* __restrict__ xs_b)
{
    int id = blockIdx.x * 256 + threadIdx.x;  // B*(T/8)*D = 2^20
    int d  = id & 2047;
    int tb = (id >> 11) & 255;
    int b  = id >> 19;
    float w0 = cw[d * 4 + 0], w1 = cw[d * 4 + 1], w2 = cw[d * 4 + 2], w3 = cw[d * 4 + 3];
    float bias = cb[d];
    int t0 = tb * 8;
    size_t base = (size_t)b * T_LEN;
    float v[11];
    #pragma unroll
    for (int i = 0; i < 11; ++i) {
        int t = t0 - 3 + i;
        v[i] = (t >= 0) ? xz[(base + t) * 4096 + d] : 0.f;
    }
    #pragma unroll
    for (int j = 0; j < 8; ++j) {
        float s = bias + w0 * v[j] + w1 * v[j + 1] + w2 * v[j + 2] + w3 * v[j + 3];
        float sl = s / (1.f + __expf(-s));
        size_t o = (base + t0 + j) * D_MODEL + d;
        xs_f[o] = sl;
        xs_b[o] = (bf16_t)sl;
    }
}

// ---------------- chunked SSM scan ----------------
// Wave wi in [0,8192): c = wi&31, dg = (wi>>5)&127, b = wi>>12.
// Lane: nq = lane&3 (state quad), dsub = lane>>2; dd = dg*16 + dsub.
// scratch layout: [c][b][dd][n] flat = (c*4096 + b*2048 + dd)*16 + n

// phase 1: local scan with zero init; store decay product + local final state
__global__ __launch_bounds__(256) void scan_phase1(
    const float* __restrict__ proj, const float* __restrict__ xs,
    const float* __restrict__ A_log,
    float* __restrict__ Aprod, float* __restrict__ hfin)
{
    int wi   = blockIdx.x * 4 + (threadIdx.x >> 6);
    int lane = threadIdx.x & 63;
    int nq   = lane & 3;
    int dsub = lane >> 2;
    int c  = wi & 31;
    int dg = (wi >> 5) & 127;
    int b  = wi >> 12;
    int dd = dg * 16 + dsub;

    float A2[4], h[4], Ap[4];
    #pragma unroll
    for (int j = 0; j < 4; ++j) {
        A2[j] = -__expf(A_log[dd * D_STATE + nq * 4 + j]) * LOG2E;
        h[j] = 0.f; Ap[j] = 1.f;
    }
    int t0 = c * L_CHUNK;
    for (int t = t0; t < t0 + L_CHUNK; ++t) {
        size_t row = (size_t)b * T_LEN + t;
        const float* pr = proj + row * N_PAD;
        float draw = pr[dd];
        float xv = xs[row * D_MODEL + dd];
        float da = fmaxf(draw, 0.f) + __logf(1.f + __expf(-fabsf(draw)));
        float dx = da * xv;
        f32x4 Bv = *(const f32x4*)(pr + D_MODEL + nq * 4);
        #pragma unroll
        for (int j = 0; j < 4; ++j) {
            float a = exp2f(da * A2[j]);
            Ap[j] *= a;
            h[j] = fmaf(a, h[j], dx * Bv[j]);
        }
    }
    size_t o = ((size_t)c * 4096 + b * 2048 + dd) * D_STATE + nq * 4;
    *(f32x4*)(Aprod + o) = f32x4{Ap[0], Ap[1], Ap[2], Ap[3]};
    *(f32x4*)(hfin  + o) = f32x4{h[0], h[1], h[2], h[3]};
}

// phase 2: serial combine across chunks. In-place converts hfin -> h_init
// per chunk, and writes the exact final state h_out.
__global__ __launch_bounds__(256) void scan_phase2(
    const float* __restrict__ h_in, const float* __restrict__ Aprod,
    float* __restrict__ hfin, float* __restrict__ h_out)
{
    int g = blockIdx.x * 256 + threadIdx.x;   // (b*2048+dd)*16+n, 65536 total
    float h = h_in[g];
    for (int c = 0; c < N_CHUNK; ++c) {
        size_t o = (size_t)c * 65536 + g;
        float a   = Aprod[o];
        float loc = hfin[o];
        hfin[o] = h;                 // becomes h_init for chunk c
        h = fmaf(a, h, loc);
    }
    h_out[g] = h;
}

// phase 3: replay each chunk from its exact initial state; emit gated y.
__global__ __launch_bounds__(256) void scan_phase3(
    const float* __restrict__ proj, const float* __restrict__ xs,
    const float* __restrict__ xz, const float* __restrict__ A_log,
    const float* __restrict__ Dv, const float* __restrict__ hinit,
    bf16_t* __restrict__ yg)
{
    int wi   = blockIdx.x * 4 + (threadIdx.x >> 6);
    int lane = threadIdx.x & 63;
    int nq   = lane & 3;
    int dsub = lane >> 2;
    int c  = wi & 31;
    int dg = (wi >> 5) & 127;
    int b  = wi >> 12;
    int dd = dg * 16 + dsub;

    float A2[4], h[4];
    size_t o = ((size_t)c * 4096 + b * 2048 + dd) * D_STATE + nq * 4;
    #pragma unroll
    for (int j = 0; j < 4; ++j) {
        A2[j] = -__expf(A_log[dd * D_STATE + nq * 4 + j]) * LOG2E;
        h[j]  = hinit[o + j];
    }
    float Dd = Dv[dd];
    int t0 = c * L_CHUNK;
    for (int t = t0; t < t0 + L_CHUNK; ++t) {
        size_t row = (size_t)b * T_LEN + t;
        const float* pr = proj + row * N_PAD;
        float draw = pr[dd];
        float xv = xs[row * D_MODEL + dd];
        float zv = xz[row * 4096 + D_MODEL + dd];
        float da = fmaxf(draw, 0.f) + __logf(1.f + __expf(-fabsf(draw)));
        float dx = da * xv;
        f32x4 Bv = *(const f32x4*)(pr + D_MODEL + nq * 4);
        f32x4 Cv = *(const f32x4*)(pr + D_MODEL + D_STATE + nq * 4);
        float yp = 0.f;
        #pragma unroll
        for (int j = 0; j < 4; ++j) {
            float a = exp2f(da * A2[j]);
            h[j] = fmaf(a, h[j], dx * Bv[j]);
            yp = fmaf(h[j], Cv[j], yp);
        }
        yp += __shfl_xor(yp, 1, 64);
        yp += __shfl_xor(yp, 2, 64);
        if (nq == 0) {
            float y = fmaf(Dd, xv, yp);
            float sz = zv / (1.f + __expf(-zv));
            yg[row * D_MODEL + dd] = (bf16_t)(y * sz);
        }
    }
}

// ---------------------------------------------------------------------------
extern "C" void kernel_launch(void* const* d_in, const int* in_sizes, int n_in,
                              void* d_out, int out_size, void* d_ws, size_t ws_size,
                              hipStream_t stream)
{
    const float* x    = (const float*)d_in[0];
    const float* h0   = (const float*)d_in[1];
    const float* nw   = (const float*)d_in[2];
    const float* w_in = (const float*)d_in[3];
    const float* cw   = (const float*)d_in[4];
    const float* cb   = (const float*)d_in[5];
    const float* w_x  = (const float*)d_in[6];
    const float* alog = (const float*)d_in[7];
    const float* dv   = (const float*)d_in[8];
    const float* w_out= (const float*)d_in[9];
    float* out  = (float*)d_out;
    float* hout = out + (size_t)N_ROWS * D_MODEL;

    char* ws = (char*)d_ws;
    size_t off = 0;
    auto alloc = [&](size_t bytes) -> void* {
        void* p = ws + off;
        off += (bytes + 255) & ~(size_t)255;
        return p;
    };
    bf16_t* W1  = (bf16_t*)alloc((size_t)4096 * 2048 * 2);   // in_proj bf16
    bf16_t* W2  = (bf16_t*)alloc((size_t)N_PAD * 2048 * 2);  // x_proj bf16 padded
    bf16_t* W3  = (bf16_t*)alloc((size_t)2048 * 2048 * 2);   // out_proj bf16
    bf16_t* XN  = (bf16_t*)alloc((size_t)N_ROWS * 2048 * 2); // normed x bf16
    float*  XZ  = (float*) alloc((size_t)N_ROWS * 4096 * 4); // in_proj out
    float*  XSf = (float*) alloc((size_t)N_ROWS * 2048 * 4); // conv+silu fp32
    float*  PROJ= (float*) alloc((size_t)N_ROWS * N_PAD * 4);// x_proj out
    // aliases (lifetimes disjoint in stream order):
    bf16_t* XSb = W1;                  // conv bf16 out (W1 dead after GEMM1)
    bf16_t* YG  = XN;                  // gated y bf16  (XN dead after GEMM1)
    // scan scratch: W1 region dead again after GEMM2 (XSb consumed).
    float* APROD = (float*)W1;
    float* HFIN  = APROD + (size_t)N_CHUNK * 4096 * D_STATE;

    // weight casts
    cast_bf16_vec<<<(4096 * 2048 / 4) / 256, 256, 0, stream>>>(w_in, W1, 4096 * 2048 / 4);
    cast_pad_w2 <<<(N_PAD * 2048) / 256, 256, 0, stream>>>(w_x, W2);
    cast_bf16_vec<<<(2048 * 2048 / 4) / 256, 256, 0, stream>>>(w_out, W3, 2048 * 2048 / 4);

    // 1) rmsnorm
    rmsnorm_kernel<<<N_ROWS, 256, 0, stream>>>(x, nw, XN);
    // 2) xz = xn @ W_in^T   (M=4096, N=4096, K=2048)
    gemm_bt<<<dim3(32, 32), 256, 0, stream>>>(XN, W1, XZ, nullptr, 2048, 4096);
    // 3) conv + silu
    conv_silu_kernel<<<(B_SZ * (T_LEN / 8) * D_MODEL) / 256, 256, 0, stream>>>(XZ, cw, cb, XSf, XSb);
    // 4) proj = xssm @ W_x^T  (N=2176 padded)
    gemm_bt<<<dim3(32, N_PAD / 128), 256, 0, stream>>>(XSb, W2, PROJ, nullptr, 2048, N_PAD);
    // 5) chunked scan: 8192 waves for phases 1/3 (full wave-slot occupancy)
    scan_phase1<<<2048, 256, 0, stream>>>(PROJ, XSf, alog, APROD, HFIN);
    scan_phase2<<<256, 256, 0, stream>>>(h0, APROD, HFIN, hout);
    scan_phase3<<<2048, 256, 0, stream>>>(PROJ, XSf, XZ, alog, dv, HFIN, YG);
    // 6) out = x + yg @ W_out^T
    gemm_bt<<<dim3(32, 16), 256, 0, stream>>>(YG, W3, out, x, 2048, 2048);

    (void)in_sizes; (void)n_in; (void)out_size; (void)ws_size;
}

// Round 4
// 579.118 us; speedup vs baseline: 4.4165x; 1.0470x over previous
//
#include <hip/hip_runtime.h>
#include <cstdint>
#include <cstddef>

// ---------------------------------------------------------------------------
// JambaMambaBlock on MI355X (gfx950)
// Pipeline: rmsnorm -> GEMM1(in_proj) -> depthwise conv+silu -> GEMM2(x_proj)
//           -> chunked SSM scan (3 phases) -> GEMM3(out_proj, +residual)
// GEMMs: bf16 MFMA 16x16x32, 128x128 tile, global_load_lds(16B) staging.
// Scan: 32 chunks of 64 steps; 4 lanes per d-channel (4 states each);
//       depth-4 register prefetch along t (round-3 showed the scan is
//       outstanding-bytes limited: 557 GB/s with ~1 iter of loads in flight).
// ---------------------------------------------------------------------------

typedef __bf16 bf16_t;
typedef __attribute__((ext_vector_type(8))) __bf16 bf16x8;
typedef __attribute__((ext_vector_type(4))) __bf16 bf16x4;
typedef __attribute__((ext_vector_type(4))) float f32x4;

#define D_MODEL 2048
#define D_STATE 16
#define B_SZ 2
#define T_LEN 2048
#define N_ROWS (B_SZ * T_LEN)        // 4096
#define N_PAD  2176                  // x_proj rows padded 2080 -> 17*128
#define N_CHUNK 32
#define L_CHUNK (T_LEN / N_CHUNK)    // 64
#define LOG2E 1.4426950408889634f

__device__ __forceinline__ void load_lds16(const void* g, void* l) {
    __builtin_amdgcn_global_load_lds(
        (const __attribute__((address_space(1))) void*)(uintptr_t)g,
        (__attribute__((address_space(3))) void*)(uintptr_t)l,
        16, 0, 0);
}

// ---------------- weight casts ----------------
__global__ __launch_bounds__(256) void cast_bf16_vec(
    const float* __restrict__ s, bf16_t* __restrict__ d, int n4)
{
    int i = blockIdx.x * 256 + threadIdx.x;
    if (i < n4) {
        f32x4 v = ((const f32x4*)s)[i];
        ((bf16x4*)d)[i] = __builtin_convertvector(v, bf16x4);
    }
}

// x_proj_w (2080 x 2048) -> bf16 padded to (2176 x 2048), pad rows zero
__global__ __launch_bounds__(256) void cast_pad_w2(
    const float* __restrict__ s, bf16_t* __restrict__ d)
{
    int i = blockIdx.x * 256 + threadIdx.x;   // over 2176*2048
    int row = i >> 11;
    int col = i & 2047;
    float v = (row < 2080) ? s[(size_t)row * 2048 + col] : 0.f;
    d[i] = (bf16_t)v;
}

// ---------------- rmsnorm -> bf16 ----------------
__global__ __launch_bounds__(256) void rmsnorm_kernel(
    const float* __restrict__ x, const float* __restrict__ w,
    bf16_t* __restrict__ xn)
{
    int row = blockIdx.x;
    int tid = threadIdx.x;
    const float* xr = x + (size_t)row * D_MODEL;
    float ss = 0.f;
    for (int i = tid; i < D_MODEL; i += 256) { float v = xr[i]; ss = fmaf(v, v, ss); }
    #pragma unroll
    for (int o = 32; o > 0; o >>= 1) ss += __shfl_down(ss, o, 64);
    __shared__ float red[4];
    if ((tid & 63) == 0) red[tid >> 6] = ss;
    __syncthreads();
    float tot = red[0] + red[1] + red[2] + red[3];
    float scale = rsqrtf(tot * (1.f / D_MODEL) + 1e-6f);
    bf16_t* xo = xn + (size_t)row * D_MODEL;
    for (int i = tid; i < D_MODEL; i += 256) xo[i] = (bf16_t)(xr[i] * scale * w[i]);
}

// ---------------- bf16 GEMM: C[M,N] = A[M,K] @ B[N,K]^T (+addend) ----------
__global__ __launch_bounds__(256) void gemm_bt(
    const bf16_t* __restrict__ A, const bf16_t* __restrict__ B,
    float* __restrict__ C, const float* __restrict__ add,
    int K, int ldc)
{
    __shared__ __align__(16) bf16_t lA[128 * 32];
    __shared__ __align__(16) bf16_t lB[128 * 32];
    const int tid = threadIdx.x;
    const int bm = blockIdx.x, bn = blockIdx.y;

    const int rA = tid >> 2;            // 0..63
    const int cA = (tid & 3) * 8;       // 0,8,16,24
    const bf16_t* aSrc = A + ((size_t)bm * 128 + rA) * K + cA;
    const bf16_t* bSrc = B + ((size_t)bn * 128 + rA) * K + cA;

    const int lane = tid & 63;
    const int wave = tid >> 6;
    const int wm = (wave & 1) * 64;
    const int wn = (wave >> 1) * 64;
    const int fr = lane & 15;
    const int quad = lane >> 4;
    const int aOff = (wm + fr) * 32 + quad * 8;
    const int bOff = (wn + fr) * 32 + quad * 8;

    f32x4 acc[4][4];
    #pragma unroll
    for (int i = 0; i < 4; ++i)
        #pragma unroll
        for (int j = 0; j < 4; ++j) acc[i][j] = {0.f, 0.f, 0.f, 0.f};

    const int kIters = K >> 5;
    for (int kt = 0; kt < kIters; ++kt) {
        load_lds16(aSrc,                  &lA[tid * 8]);
        load_lds16(aSrc + (size_t)64 * K, &lA[2048 + tid * 8]);
        load_lds16(bSrc,                  &lB[tid * 8]);
        load_lds16(bSrc + (size_t)64 * K, &lB[2048 + tid * 8]);
        aSrc += 32; bSrc += 32;
        __syncthreads();

        bf16x8 af[4], bv[4];
        #pragma unroll
        for (int i = 0; i < 4; ++i) af[i] = *(const bf16x8*)(&lA[aOff + i * 512]);
        #pragma unroll
        for (int j = 0; j < 4; ++j) bv[j] = *(const bf16x8*)(&lB[bOff + j * 512]);
        #pragma unroll
        for (int i = 0; i < 4; ++i)
            #pragma unroll
            for (int j = 0; j < 4; ++j)
                acc[i][j] = __builtin_amdgcn_mfma_f32_16x16x32_bf16(
                    af[i], bv[j], acc[i][j], 0, 0, 0);
        __syncthreads();
    }

    const size_t row0 = (size_t)bm * 128 + wm + quad * 4;
    const size_t col0 = (size_t)bn * 128 + wn + fr;
    #pragma unroll
    for (int i = 0; i < 4; ++i) {
        #pragma unroll
        for (int r = 0; r < 4; ++r) {
            size_t row = row0 + i * 16 + r;
            float* crow = C + row * (size_t)ldc + col0;
            const float* arow = add ? (add + row * (size_t)ldc + col0) : (const float*)nullptr;
            #pragma unroll
            for (int j = 0; j < 4; ++j) {
                float v = acc[i][j][r];
                if (arow) v += arow[j * 16];
                crow[j * 16] = v;
            }
        }
    }
}

// ---------------- depthwise causal conv(4) + silu (bf16 out only) ---------
__global__ __launch_bounds__(256) void conv_silu_kernel(
    const float* __restrict__ xz, const float* __restrict__ cw,
    const float* __restrict__ cb, bf16_t* __restrict__ xs_b)
{
    int id = blockIdx.x * 256 + threadIdx.x;  // B*(T/8)*D = 2^20
    int d  = id & 2047;
    int tb = (id >> 11) & 255;
    int b  = id >> 19;
    float w0 = cw[d * 4 + 0], w1 = cw[d * 4 + 1], w2 = cw[d * 4 + 2], w3 = cw[d * 4 + 3];
    float bias = cb[d];
    int t0 = tb * 8;
    size_t base = (size_t)b * T_LEN;
    float v[11];
    #pragma unroll
    for (int i = 0; i < 11; ++i) {
        int t = t0 - 3 + i;
        v[i] = (t >= 0) ? xz[(base + t) * 4096 + d] : 0.f;
    }
    #pragma unroll
    for (int j = 0; j < 8; ++j) {
        float s = bias + w0 * v[j] + w1 * v[j + 1] + w2 * v[j + 2] + w3 * v[j + 3];
        float sl = s / (1.f + __expf(-s));
        xs_b[(base + t0 + j) * D_MODEL + d] = (bf16_t)sl;
    }
}

// ---------------- chunked SSM scan ----------------
// Wave wi in [0,8192): c = wi&31, dg = (wi>>5)&127, b = wi>>12.
// Lane: nq = lane&3 (state quad), dsub = lane>>2; dd = dg*16 + dsub.
// scratch layout: [c][b][dd][n] flat = (c*4096 + b*2048 + dd)*16 + n
#define PF 4   // prefetch depth (register slots)

// phase 1: local scan with zero init; store decay product + local final state
__global__ __launch_bounds__(256) void scan_phase1(
    const float* __restrict__ proj, const bf16_t* __restrict__ xs,
    const float* __restrict__ A_log,
    float* __restrict__ Aprod, float* __restrict__ hfin)
{
    int wi   = blockIdx.x * 4 + (threadIdx.x >> 6);
    int lane = threadIdx.x & 63;
    int nq   = lane & 3;
    int dsub = lane >> 2;
    int c  = wi & 31;
    int dg = (wi >> 5) & 127;
    int b  = wi >> 12;
    int dd = dg * 16 + dsub;

    float A2[4], h[4], Ap[4];
    #pragma unroll
    for (int j = 0; j < 4; ++j) {
        A2[j] = -__expf(A_log[dd * D_STATE + nq * 4 + j]) * LOG2E;
        h[j] = 0.f; Ap[j] = 1.f;
    }
    const int t0 = c * L_CHUNK;
    const int tmax = t0 + L_CHUNK - 1;

    float p_draw[PF], p_xv[PF];
    f32x4 p_B[PF];
    #pragma unroll
    for (int u = 0; u < PF; ++u) {
        size_t row = (size_t)b * T_LEN + t0 + u;
        const float* pr = proj + row * N_PAD;
        p_draw[u] = pr[dd];
        p_xv[u]   = (float)xs[row * D_MODEL + dd];
        p_B[u]    = *(const f32x4*)(pr + D_MODEL + nq * 4);
    }

    for (int it = 0; it < L_CHUNK; it += PF) {
        #pragma unroll
        for (int u = 0; u < PF; ++u) {
            int t = t0 + it + u;
            float draw = p_draw[u], xv = p_xv[u];
            f32x4 Bv = p_B[u];
            // issue prefetch for t+PF (clamped; refetch of tmax is harmless)
            int tn = t + PF; tn = (tn > tmax) ? tmax : tn;
            {
                size_t row = (size_t)b * T_LEN + tn;
                const float* pr = proj + row * N_PAD;
                p_draw[u] = pr[dd];
                p_xv[u]   = (float)xs[row * D_MODEL + dd];
                p_B[u]    = *(const f32x4*)(pr + D_MODEL + nq * 4);
            }
            float da = fmaxf(draw, 0.f) + __logf(1.f + __expf(-fabsf(draw)));
            float dx = da * xv;
            #pragma unroll
            for (int j = 0; j < 4; ++j) {
                float a = exp2f(da * A2[j]);
                Ap[j] *= a;
                h[j] = fmaf(a, h[j], dx * Bv[j]);
            }
        }
    }
    size_t o = ((size_t)c * 4096 + b * 2048 + dd) * D_STATE + nq * 4;
    *(f32x4*)(Aprod + o) = f32x4{Ap[0], Ap[1], Ap[2], Ap[3]};
    *(f32x4*)(hfin  + o) = f32x4{h[0], h[1], h[2], h[3]};
}

// phase 2: serial combine across chunks. In-place converts hfin -> h_init
// per chunk, and writes the exact final state h_out.
__global__ __launch_bounds__(256) void scan_phase2(
    const float* __restrict__ h_in, const float* __restrict__ Aprod,
    float* __restrict__ hfin, float* __restrict__ h_out)
{
    int g = blockIdx.x * 256 + threadIdx.x;   // (b*2048+dd)*16+n, 65536 total
    float h = h_in[g];
    for (int c = 0; c < N_CHUNK; ++c) {
        size_t o = (size_t)c * 65536 + g;
        float a   = Aprod[o];
        float loc = hfin[o];
        hfin[o] = h;                 // becomes h_init for chunk c
        h = fmaf(a, h, loc);
    }
    h_out[g] = h;
}

// phase 3: replay each chunk from its exact initial state; emit gated y.
__global__ __launch_bounds__(256) void scan_phase3(
    const float* __restrict__ proj, const bf16_t* __restrict__ xs,
    const float* __restrict__ xz, const float* __restrict__ A_log,
    const float* __restrict__ Dv, const float* __restrict__ hinit,
    bf16_t* __restrict__ yg)
{
    int wi   = blockIdx.x * 4 + (threadIdx.x >> 6);
    int lane = threadIdx.x & 63;
    int nq   = lane & 3;
    int dsub = lane >> 2;
    int c  = wi & 31;
    int dg = (wi >> 5) & 127;
    int b  = wi >> 12;
    int dd = dg * 16 + dsub;

    float A2[4], h[4];
    size_t o = ((size_t)c * 4096 + b * 2048 + dd) * D_STATE + nq * 4;
    #pragma unroll
    for (int j = 0; j < 4; ++j) {
        A2[j] = -__expf(A_log[dd * D_STATE + nq * 4 + j]) * LOG2E;
        h[j]  = hinit[o + j];
    }
    float Dd = Dv[dd];
    const int t0 = c * L_CHUNK;
    const int tmax = t0 + L_CHUNK - 1;

    float p_draw[PF], p_xv[PF], p_zv[PF];
    f32x4 p_B[PF], p_C[PF];
    #pragma unroll
    for (int u = 0; u < PF; ++u) {
        size_t row = (size_t)b * T_LEN + t0 + u;
        const float* pr = proj + row * N_PAD;
        p_draw[u] = pr[dd];
        p_xv[u]   = (float)xs[row * D_MODEL + dd];
        p_zv[u]   = xz[row * 4096 + D_MODEL + dd];
        p_B[u]    = *(const f32x4*)(pr + D_MODEL + nq * 4);
        p_C[u]    = *(const f32x4*)(pr + D_MODEL + D_STATE + nq * 4);
    }

    for (int it = 0; it < L_CHUNK; it += PF) {
        #pragma unroll
        for (int u = 0; u < PF; ++u) {
            int t = t0 + it + u;
            float draw = p_draw[u], xv = p_xv[u], zv = p_zv[u];
            f32x4 Bv = p_B[u], Cv = p_C[u];
            int tn = t + PF; tn = (tn > tmax) ? tmax : tn;
            {
                size_t row = (size_t)b * T_LEN + tn;
                const float* pr = proj + row * N_PAD;
                p_draw[u] = pr[dd];
                p_xv[u]   = (float)xs[row * D_MODEL + dd];
                p_zv[u]   = xz[row * 4096 + D_MODEL + dd];
                p_B[u]    = *(const f32x4*)(pr + D_MODEL + nq * 4);
                p_C[u]    = *(const f32x4*)(pr + D_MODEL + D_STATE + nq * 4);
            }
            float da = fmaxf(draw, 0.f) + __logf(1.f + __expf(-fabsf(draw)));
            float dx = da * xv;
            float yp = 0.f;
            #pragma unroll
            for (int j = 0; j < 4; ++j) {
                float a = exp2f(da * A2[j]);
                h[j] = fmaf(a, h[j], dx * Bv[j]);
                yp = fmaf(h[j], Cv[j], yp);
            }
            yp += __shfl_xor(yp, 1, 64);
            yp += __shfl_xor(yp, 2, 64);
            if (nq == 0) {
                float y = fmaf(Dd, xv, yp);
                float sz = zv / (1.f + __expf(-zv));
                yg[((size_t)b * T_LEN + t) * D_MODEL + dd] = (bf16_t)(y * sz);
            }
        }
    }
}

// ---------------------------------------------------------------------------
extern "C" void kernel_launch(void* const* d_in, const int* in_sizes, int n_in,
                              void* d_out, int out_size, void* d_ws, size_t ws_size,
                              hipStream_t stream)
{
    const float* x    = (const float*)d_in[0];
    const float* h0   = (const float*)d_in[1];
    const float* nw   = (const float*)d_in[2];
    const float* w_in = (const float*)d_in[3];
    const float* cw   = (const float*)d_in[4];
    const float* cb   = (const float*)d_in[5];
    const float* w_x  = (const float*)d_in[6];
    const float* alog = (const float*)d_in[7];
    const float* dv   = (const float*)d_in[8];
    const float* w_out= (const float*)d_in[9];
    float* out  = (float*)d_out;
    float* hout = out + (size_t)N_ROWS * D_MODEL;

    char* ws = (char*)d_ws;
    size_t off = 0;
    auto alloc = [&](size_t bytes) -> void* {
        void* p = ws + off;
        off += (bytes + 255) & ~(size_t)255;
        return p;
    };
    bf16_t* W1  = (bf16_t*)alloc((size_t)4096 * 2048 * 2);   // in_proj bf16
    bf16_t* W2  = (bf16_t*)alloc((size_t)N_PAD * 2048 * 2);  // x_proj bf16 padded
    bf16_t* W3  = (bf16_t*)alloc((size_t)2048 * 2048 * 2);   // out_proj bf16
    bf16_t* XN  = (bf16_t*)alloc((size_t)N_ROWS * 2048 * 2); // normed x bf16
    float*  XZ  = (float*) alloc((size_t)N_ROWS * 4096 * 4); // in_proj out
    float*  PROJ= (float*) alloc((size_t)N_ROWS * N_PAD * 4);// x_proj out
    float* APROD= (float*) alloc((size_t)N_CHUNK * 4096 * D_STATE * 4);
    float* HFIN = (float*) alloc((size_t)N_CHUNK * 4096 * D_STATE * 4);
    // aliases (lifetimes disjoint in stream order):
    bf16_t* XSb = W1;   // conv bf16 out (W1 dead after GEMM1; lives thru scan)
    bf16_t* YG  = XN;   // gated y bf16  (XN dead after GEMM1)

    // weight casts
    cast_bf16_vec<<<(4096 * 2048 / 4) / 256, 256, 0, stream>>>(w_in, W1, 4096 * 2048 / 4);
    cast_pad_w2 <<<(N_PAD * 2048) / 256, 256, 0, stream>>>(w_x, W2);
    cast_bf16_vec<<<(2048 * 2048 / 4) / 256, 256, 0, stream>>>(w_out, W3, 2048 * 2048 / 4);

    // 1) rmsnorm
    rmsnorm_kernel<<<N_ROWS, 256, 0, stream>>>(x, nw, XN);
    // 2) xz = xn @ W_in^T   (M=4096, N=4096, K=2048)
    gemm_bt<<<dim3(32, 32), 256, 0, stream>>>(XN, W1, XZ, nullptr, 2048, 4096);
    // 3) conv + silu (bf16 only; scan reads the bf16 copy)
    conv_silu_kernel<<<(B_SZ * (T_LEN / 8) * D_MODEL) / 256, 256, 0, stream>>>(XZ, cw, cb, XSb);
    // 4) proj = xssm @ W_x^T  (N=2176 padded)
    gemm_bt<<<dim3(32, N_PAD / 128), 256, 0, stream>>>(XSb, W2, PROJ, nullptr, 2048, N_PAD);
    // 5) chunked scan: 8192 waves, depth-4 register prefetch
    scan_phase1<<<2048, 256, 0, stream>>>(PROJ, XSb, alog, APROD, HFIN);
    scan_phase2<<<256, 256, 0, stream>>>(h0, APROD, HFIN, hout);
    scan_phase3<<<2048, 256, 0, stream>>>(PROJ, XSb, XZ, alog, dv, HFIN, YG);
    // 6) out = x + yg @ W_out^T
    gemm_bt<<<dim3(32, 16), 256, 0, stream>>>(YG, W3, out, x, 2048, 2048);

    (void)in_sizes; (void)n_in; (void)out_size; (void)ws_size;
}

// Round 5
// 525.278 us; speedup vs baseline: 4.8692x; 1.1025x over previous
//
#include <hip/hip_runtime.h>
#include <cstdint>
#include <cstddef>

// ---------------------------------------------------------------------------
// JambaMambaBlock on MI355X (gfx950)
// Pipeline: rmsnorm -> GEMM1(in_proj, split epilogue: x fp32 / silu(z) bf16)
//           -> depthwise conv+silu -> GEMM2(x_proj, softplus epilogue)
//           -> chunked SSM scan (3 phases) -> GEMM3(out_proj, +residual)
// GEMMs: bf16 MFMA 16x16x32, 128x128 tile, global_load_lds(16B) staging,
//        LDS-staged coalesced float4 epilogue (round-4: 64 scattered dword
//        stores/thread were ~40 us of GEMM1's 120).
// Scan: 32 chunks of 64 steps; 4 lanes per d-channel; depth-4 reg prefetch.
// ---------------------------------------------------------------------------

typedef __bf16 bf16_t;
typedef __attribute__((ext_vector_type(8))) __bf16 bf16x8;
typedef __attribute__((ext_vector_type(4))) __bf16 bf16x4;
typedef __attribute__((ext_vector_type(4))) float f32x4;

#define D_MODEL 2048
#define D_STATE 16
#define B_SZ 2
#define T_LEN 2048
#define N_ROWS (B_SZ * T_LEN)        // 4096
#define N_PAD  2176                  // x_proj rows padded 2080 -> 17*128
#define N_CHUNK 32
#define L_CHUNK (T_LEN / N_CHUNK)    // 64
#define LOG2E 1.4426950408889634f

__device__ __forceinline__ void load_lds16(const void* g, void* l) {
    __builtin_amdgcn_global_load_lds(
        (const __attribute__((address_space(1))) void*)(uintptr_t)g,
        (__attribute__((address_space(3))) void*)(uintptr_t)l,
        16, 0, 0);
}

// ---------------- weight casts ----------------
__global__ __launch_bounds__(256) void cast_w13(
    const float* __restrict__ w1, const float* __restrict__ w3,
    bf16_t* __restrict__ d1, bf16_t* __restrict__ d3)
{
    int i = blockIdx.x * 256 + threadIdx.x;
    const int n1 = 4096 * 2048 / 4;
    if (i < n1) {
        f32x4 v = ((const f32x4*)w1)[i];
        ((bf16x4*)d1)[i] = __builtin_convertvector(v, bf16x4);
    } else {
        int j = i - n1;      // < 2048*2048/4
        f32x4 v = ((const f32x4*)w3)[j];
        ((bf16x4*)d3)[j] = __builtin_convertvector(v, bf16x4);
    }
}

// x_proj_w (2080 x 2048) -> bf16 padded to (2176 x 2048), pad rows zero
__global__ __launch_bounds__(256) void cast_pad_w2(
    const float* __restrict__ s, bf16_t* __restrict__ d)
{
    int i = blockIdx.x * 256 + threadIdx.x;   // over 2176*2048
    int row = i >> 11;
    int col = i & 2047;
    float v = (row < 2080) ? s[(size_t)row * 2048 + col] : 0.f;
    d[i] = (bf16_t)v;
}

// ---------------- rmsnorm -> bf16 ----------------
__global__ __launch_bounds__(256) void rmsnorm_kernel(
    const float* __restrict__ x, const float* __restrict__ w,
    bf16_t* __restrict__ xn)
{
    int row = blockIdx.x;
    int tid = threadIdx.x;
    const float* xr = x + (size_t)row * D_MODEL;
    float ss = 0.f;
    for (int i = tid; i < D_MODEL; i += 256) { float v = xr[i]; ss = fmaf(v, v, ss); }
    #pragma unroll
    for (int o = 32; o > 0; o >>= 1) ss += __shfl_down(ss, o, 64);
    __shared__ float red[4];
    if ((tid & 63) == 0) red[tid >> 6] = ss;
    __syncthreads();
    float tot = red[0] + red[1] + red[2] + red[3];
    float scale = rsqrtf(tot * (1.f / D_MODEL) + 1e-6f);
    bf16_t* xo = xn + (size_t)row * D_MODEL;
    for (int i = tid; i < D_MODEL; i += 256) xo[i] = (bf16_t)(xr[i] * scale * w[i]);
}

// ---------------- bf16 GEMM: C[M,N] = A[M,K] @ B[N,K]^T ----------
// MODE 0 (GEMM1): cols<2048 -> out0 fp32 (ldc 2048);
//                 cols>=2048 -> out1 = bf16 silu(v) (ldc 2048, col-2048)
// MODE 1 (GEMM2): out0 fp32 ldc N_PAD; softplus applied when bn<16
// MODE 2 (GEMM3): out0 = v + add, fp32 ldc 2048
template<int MODE>
__global__ __launch_bounds__(256) void gemm_bt(
    const bf16_t* __restrict__ A, const bf16_t* __restrict__ B, int K,
    float* __restrict__ out0, bf16_t* __restrict__ out1,
    const float* __restrict__ add)
{
    __shared__ __align__(16) bf16_t lA[128 * 32];
    __shared__ __align__(16) bf16_t lB[128 * 32];
    __shared__ __align__(16) float cs[32 * 132];   // epilogue strip, pad 132
    const int tid = threadIdx.x;
    const int bm = blockIdx.x, bn = blockIdx.y;

    const int rA = tid >> 2;            // 0..63
    const int cA = (tid & 3) * 8;       // 0,8,16,24
    const bf16_t* aSrc = A + ((size_t)bm * 128 + rA) * K + cA;
    const bf16_t* bSrc = B + ((size_t)bn * 128 + rA) * K + cA;

    const int lane = tid & 63;
    const int wave = tid >> 6;
    const int wm = (wave & 1) * 64;
    const int wn = (wave >> 1) * 64;
    const int fr = lane & 15;
    const int quad = lane >> 4;
    const int aOff = (wm + fr) * 32 + quad * 8;
    const int bOff = (wn + fr) * 32 + quad * 8;

    f32x4 acc[4][4];
    #pragma unroll
    for (int i = 0; i < 4; ++i)
        #pragma unroll
        for (int j = 0; j < 4; ++j) acc[i][j] = {0.f, 0.f, 0.f, 0.f};

    const int kIters = K >> 5;
    for (int kt = 0; kt < kIters; ++kt) {
        load_lds16(aSrc,                  &lA[tid * 8]);
        load_lds16(aSrc + (size_t)64 * K, &lA[2048 + tid * 8]);
        load_lds16(bSrc,                  &lB[tid * 8]);
        load_lds16(bSrc + (size_t)64 * K, &lB[2048 + tid * 8]);
        aSrc += 32; bSrc += 32;
        __syncthreads();

        bf16x8 af[4], bv[4];
        #pragma unroll
        for (int i = 0; i < 4; ++i) af[i] = *(const bf16x8*)(&lA[aOff + i * 512]);
        #pragma unroll
        for (int j = 0; j < 4; ++j) bv[j] = *(const bf16x8*)(&lB[bOff + j * 512]);
        #pragma unroll
        for (int i = 0; i < 4; ++i)
            #pragma unroll
            for (int j = 0; j < 4; ++j)
                acc[i][j] = __builtin_amdgcn_mfma_f32_16x16x32_bf16(
                    af[i], bv[j], acc[i][j], 0, 0, 0);
        __syncthreads();
    }

    // ---- LDS-staged coalesced epilogue, 4 strips of 32 rows x 128 cols ----
    // acc element (i,j,rr): global row = bm*128 + wm + i*16 + quad*4 + rr,
    //                       global col = bn*128 + wn + j*16 + fr
    const int lrow0 = (wave & 1) * 16 + quad * 4;
    const int lcol0 = wn + fr;
    for (int i = 0; i < 4; ++i) {
        __syncthreads();
        #pragma unroll
        for (int j = 0; j < 4; ++j)
            #pragma unroll
            for (int rr = 0; rr < 4; ++rr)
                cs[(lrow0 + rr) * 132 + lcol0 + j * 16] = acc[i][j][rr];
        __syncthreads();
        #pragma unroll
        for (int k = 0; k < 4; ++k) {
            int f4  = tid + k * 256;       // 0..1023
            int row = f4 >> 5;             // 0..31
            int c4  = (f4 & 31) * 4;       // 0..124
            f32x4 v = *(const f32x4*)&cs[row * 132 + c4];
            int gr = bm * 128 + i * 16 + ((row < 16) ? row : (48 + row));
            int gc = bn * 128 + c4;
            if (MODE == 0) {
                if (bn < 16) {
                    *(f32x4*)&out0[(size_t)gr * 2048 + gc] = v;
                } else {
                    bf16x4 o;
                    #pragma unroll
                    for (int e = 0; e < 4; ++e) {
                        float s = v[e];
                        o[e] = (bf16_t)(s / (1.f + __expf(-s)));
                    }
                    *(bf16x4*)&out1[(size_t)gr * 2048 + (gc - 2048)] = o;
                }
            } else if (MODE == 1) {
                if (bn < 16) {
                    #pragma unroll
                    for (int e = 0; e < 4; ++e) {
                        float s = v[e];
                        v[e] = fmaxf(s, 0.f) + __logf(1.f + __expf(-fabsf(s)));
                    }
                }
                *(f32x4*)&out0[(size_t)gr * N_PAD + gc] = v;
            } else {
                f32x4 a4 = *(const f32x4*)&add[(size_t)gr * 2048 + gc];
                v = v + a4;
                *(f32x4*)&out0[(size_t)gr * 2048 + gc] = v;
            }
        }
    }
}

// ---------------- depthwise causal conv(4) + silu (bf16 out) ----------
// xb: x-branch fp32, pitch 2048
__global__ __launch_bounds__(256) void conv_silu_kernel(
    const float* __restrict__ xb, const float* __restrict__ cw,
    const float* __restrict__ cb, bf16_t* __restrict__ xs_b)
{
    int id = blockIdx.x * 256 + threadIdx.x;  // B*(T/8)*D = 2^20
    int d  = id & 2047;
    int tb = (id >> 11) & 255;
    int b  = id >> 19;
    float w0 = cw[d * 4 + 0], w1 = cw[d * 4 + 1], w2 = cw[d * 4 + 2], w3 = cw[d * 4 + 3];
    float bias = cb[d];
    int t0 = tb * 8;
    size_t base = (size_t)b * T_LEN;
    float v[11];
    #pragma unroll
    for (int i = 0; i < 11; ++i) {
        int t = t0 - 3 + i;
        v[i] = (t >= 0) ? xb[(base + t) * 2048 + d] : 0.f;
    }
    #pragma unroll
    for (int j = 0; j < 8; ++j) {
        float s = bias + w0 * v[j] + w1 * v[j + 1] + w2 * v[j + 2] + w3 * v[j + 3];
        float sl = s / (1.f + __expf(-s));
        xs_b[(base + t0 + j) * D_MODEL + d] = (bf16_t)sl;
    }
}

// ---------------- chunked SSM scan ----------------
// Wave wi in [0,8192): c = wi&31, dg = (wi>>5)&127, b = wi>>12.
// Lane: nq = lane&3 (state quad), dsub = lane>>2; dd = dg*16 + dsub.
// proj cols <2048 now hold da = softplus(delta_raw) (from GEMM2 epilogue).
// scratch layout: [c][b][dd][n] flat = (c*4096 + b*2048 + dd)*16 + n
#define PF 4   // prefetch depth (register slots)

// phase 1: local scan with zero init; store decay product + local final state
__global__ __launch_bounds__(256) void scan_phase1(
    const float* __restrict__ proj, const bf16_t* __restrict__ xs,
    const float* __restrict__ A_log,
    float* __restrict__ Aprod, float* __restrict__ hfin)
{
    int wi   = blockIdx.x * 4 + (threadIdx.x >> 6);
    int lane = threadIdx.x & 63;
    int nq   = lane & 3;
    int dsub = lane >> 2;
    int c  = wi & 31;
    int dg = (wi >> 5) & 127;
    int b  = wi >> 12;
    int dd = dg * 16 + dsub;

    float A2[4], h[4], Ap[4];
    #pragma unroll
    for (int j = 0; j < 4; ++j) {
        A2[j] = -__expf(A_log[dd * D_STATE + nq * 4 + j]) * LOG2E;
        h[j] = 0.f; Ap[j] = 1.f;
    }
    const int t0 = c * L_CHUNK;
    const int tmax = t0 + L_CHUNK - 1;

    float p_da[PF], p_xv[PF];
    f32x4 p_B[PF];
    #pragma unroll
    for (int u = 0; u < PF; ++u) {
        size_t row = (size_t)b * T_LEN + t0 + u;
        const float* pr = proj + row * N_PAD;
        p_da[u] = pr[dd];
        p_xv[u] = (float)xs[row * D_MODEL + dd];
        p_B[u]  = *(const f32x4*)(pr + D_MODEL + nq * 4);
    }

    for (int it = 0; it < L_CHUNK; it += PF) {
        #pragma unroll
        for (int u = 0; u < PF; ++u) {
            int t = t0 + it + u;
            float da = p_da[u], xv = p_xv[u];
            f32x4 Bv = p_B[u];
            int tn = t + PF; tn = (tn > tmax) ? tmax : tn;
            {
                size_t row = (size_t)b * T_LEN + tn;
                const float* pr = proj + row * N_PAD;
                p_da[u] = pr[dd];
                p_xv[u] = (float)xs[row * D_MODEL + dd];
                p_B[u]  = *(const f32x4*)(pr + D_MODEL + nq * 4);
            }
            float dx = da * xv;
            #pragma unroll
            for (int j = 0; j < 4; ++j) {
                float a = exp2f(da * A2[j]);
                Ap[j] *= a;
                h[j] = fmaf(a, h[j], dx * Bv[j]);
            }
        }
    }
    size_t o = ((size_t)c * 4096 + b * 2048 + dd) * D_STATE + nq * 4;
    *(f32x4*)(Aprod + o) = f32x4{Ap[0], Ap[1], Ap[2], Ap[3]};
    *(f32x4*)(hfin  + o) = f32x4{h[0], h[1], h[2], h[3]};
}

// phase 2: serial combine across chunks. In-place converts hfin -> h_init
// per chunk, and writes the exact final state h_out.
__global__ __launch_bounds__(256) void scan_phase2(
    const float* __restrict__ h_in, const float* __restrict__ Aprod,
    float* __restrict__ hfin, float* __restrict__ h_out)
{
    int g = blockIdx.x * 256 + threadIdx.x;   // (b*2048+dd)*16+n, 65536 total
    float h = h_in[g];
    for (int c = 0; c < N_CHUNK; ++c) {
        size_t o = (size_t)c * 65536 + g;
        float a   = Aprod[o];
        float loc = hfin[o];
        hfin[o] = h;                 // becomes h_init for chunk c
        h = fmaf(a, h, loc);
    }
    h_out[g] = h;
}

// phase 3: replay each chunk from its exact initial state; emit gated y.
// zg holds silu(z) in bf16 (from GEMM1 epilogue).
__global__ __launch_bounds__(256) void scan_phase3(
    const float* __restrict__ proj, const bf16_t* __restrict__ xs,
    const bf16_t* __restrict__ zg, const float* __restrict__ A_log,
    const float* __restrict__ Dv, const float* __restrict__ hinit,
    bf16_t* __restrict__ yg)
{
    int wi   = blockIdx.x * 4 + (threadIdx.x >> 6);
    int lane = threadIdx.x & 63;
    int nq   = lane & 3;
    int dsub = lane >> 2;
    int c  = wi & 31;
    int dg = (wi >> 5) & 127;
    int b  = wi >> 12;
    int dd = dg * 16 + dsub;

    float A2[4], h[4];
    size_t o = ((size_t)c * 4096 + b * 2048 + dd) * D_STATE + nq * 4;
    #pragma unroll
    for (int j = 0; j < 4; ++j) {
        A2[j] = -__expf(A_log[dd * D_STATE + nq * 4 + j]) * LOG2E;
        h[j]  = hinit[o + j];
    }
    float Dd = Dv[dd];
    const int t0 = c * L_CHUNK;
    const int tmax = t0 + L_CHUNK - 1;

    float p_da[PF], p_xv[PF], p_sz[PF];
    f32x4 p_B[PF], p_C[PF];
    #pragma unroll
    for (int u = 0; u < PF; ++u) {
        size_t row = (size_t)b * T_LEN + t0 + u;
        const float* pr = proj + row * N_PAD;
        p_da[u] = pr[dd];
        p_xv[u] = (float)xs[row * D_MODEL + dd];
        p_sz[u] = (float)zg[row * 2048 + dd];
        p_B[u]  = *(const f32x4*)(pr + D_MODEL + nq * 4);
        p_C[u]  = *(const f32x4*)(pr + D_MODEL + D_STATE + nq * 4);
    }

    for (int it = 0; it < L_CHUNK; it += PF) {
        #pragma unroll
        for (int u = 0; u < PF; ++u) {
            int t = t0 + it + u;
            float da = p_da[u], xv = p_xv[u], sz = p_sz[u];
            f32x4 Bv = p_B[u], Cv = p_C[u];
            int tn = t + PF; tn = (tn > tmax) ? tmax : tn;
            {
                size_t row = (size_t)b * T_LEN + tn;
                const float* pr = proj + row * N_PAD;
                p_da[u] = pr[dd];
                p_xv[u] = (float)xs[row * D_MODEL + dd];
                p_sz[u] = (float)zg[row * 2048 + dd];
                p_B[u]  = *(const f32x4*)(pr + D_MODEL + nq * 4);
                p_C[u]  = *(const f32x4*)(pr + D_MODEL + D_STATE + nq * 4);
            }
            float dx = da * xv;
            float yp = 0.f;
            #pragma unroll
            for (int j = 0; j < 4; ++j) {
                float a = exp2f(da * A2[j]);
                h[j] = fmaf(a, h[j], dx * Bv[j]);
                yp = fmaf(h[j], Cv[j], yp);
            }
            yp += __shfl_xor(yp, 1, 64);
            yp += __shfl_xor(yp, 2, 64);
            if (nq == 0) {
                float y = fmaf(Dd, xv, yp);
                yg[((size_t)b * T_LEN + t) * D_MODEL + dd] = (bf16_t)(y * sz);
            }
        }
    }
}

// ---------------------------------------------------------------------------
extern "C" void kernel_launch(void* const* d_in, const int* in_sizes, int n_in,
                              void* d_out, int out_size, void* d_ws, size_t ws_size,
                              hipStream_t stream)
{
    const float* x    = (const float*)d_in[0];
    const float* h0   = (const float*)d_in[1];
    const float* nw   = (const float*)d_in[2];
    const float* w_in = (const float*)d_in[3];
    const float* cw   = (const float*)d_in[4];
    const float* cb   = (const float*)d_in[5];
    const float* w_x  = (const float*)d_in[6];
    const float* alog = (const float*)d_in[7];
    const float* dv   = (const float*)d_in[8];
    const float* w_out= (const float*)d_in[9];
    float* out  = (float*)d_out;
    float* hout = out + (size_t)N_ROWS * D_MODEL;

    char* ws = (char*)d_ws;
    size_t off = 0;
    auto alloc = [&](size_t bytes) -> void* {
        void* p = ws + off;
        off += (bytes + 255) & ~(size_t)255;
        return p;
    };
    bf16_t* W1  = (bf16_t*)alloc((size_t)4096 * 2048 * 2);   // in_proj bf16
    bf16_t* W2  = (bf16_t*)alloc((size_t)N_PAD * 2048 * 2);  // x_proj bf16 padded
    bf16_t* W3  = (bf16_t*)alloc((size_t)2048 * 2048 * 2);   // out_proj bf16
    bf16_t* XN  = (bf16_t*)alloc((size_t)N_ROWS * 2048 * 2); // normed x bf16
    float*  XB  = (float*) alloc((size_t)N_ROWS * 2048 * 4); // x-branch fp32
    bf16_t* ZG  = (bf16_t*)alloc((size_t)N_ROWS * 2048 * 2); // silu(z) bf16
    float*  PROJ= (float*) alloc((size_t)N_ROWS * N_PAD * 4);// x_proj out (da|B|C)
    float* APROD= (float*) alloc((size_t)N_CHUNK * 4096 * D_STATE * 4);
    float* HFIN = (float*) alloc((size_t)N_CHUNK * 4096 * D_STATE * 4);
    // aliases (lifetimes disjoint in stream order):
    bf16_t* XSb = W1;   // conv bf16 out (W1 dead after GEMM1; lives thru scan)
    bf16_t* YG  = XN;   // gated y bf16  (XN dead after GEMM1)

    // weight casts
    cast_w13<<<(4096 * 2048 / 4 + 2048 * 2048 / 4) / 256, 256, 0, stream>>>(w_in, w_out, W1, W3);
    cast_pad_w2<<<(N_PAD * 2048) / 256, 256, 0, stream>>>(w_x, W2);

    // 1) rmsnorm
    rmsnorm_kernel<<<N_ROWS, 256, 0, stream>>>(x, nw, XN);
    // 2) xz = xn @ W_in^T; epilogue splits x fp32 / silu(z) bf16
    gemm_bt<0><<<dim3(32, 32), 256, 0, stream>>>(XN, W1, 2048, XB, ZG, nullptr);
    // 3) conv + silu (bf16 out)
    conv_silu_kernel<<<(B_SZ * (T_LEN / 8) * D_MODEL) / 256, 256, 0, stream>>>(XB, cw, cb, XSb);
    // 4) proj = xssm @ W_x^T; epilogue applies softplus to delta cols
    gemm_bt<1><<<dim3(32, N_PAD / 128), 256, 0, stream>>>(XSb, W2, 2048, PROJ, nullptr, nullptr);
    // 5) chunked scan: 8192 waves, depth-4 register prefetch
    scan_phase1<<<2048, 256, 0, stream>>>(PROJ, XSb, alog, APROD, HFIN);
    scan_phase2<<<256, 256, 0, stream>>>(h0, APROD, HFIN, hout);
    scan_phase3<<<2048, 256, 0, stream>>>(PROJ, XSb, ZG, alog, dv, HFIN, YG);
    // 6) out = x + yg @ W_out^T
    gemm_bt<2><<<dim3(32, 16), 256, 0, stream>>>(YG, W3, 2048, out, nullptr, x);

    (void)in_sizes; (void)n_in; (void)out_size; (void)ws_size;
}